// Round 13
// baseline (210.380 us; speedup 1.0000x reference)
//
#include <hip/hip_runtime.h>
#include <cstddef>
#include <cstdint>

#define DIM   512
#define NSEQ  1024
#define NB    4
#define LOG2E 1.44269504f

typedef unsigned short u16;
typedef short bf16x8 __attribute__((ext_vector_type(8)));
typedef _Float16 half8v __attribute__((ext_vector_type(8)));
typedef float f32x4  __attribute__((ext_vector_type(4)));

#define MFMA(a, b, c)  __builtin_amdgcn_mfma_f32_16x16x32_bf16(a, b, c, 0, 0, 0)
#define MFMAH(a, b, c) __builtin_amdgcn_mfma_f32_16x16x32_f16(a, b, c, 0, 0, 0)

// RNE fp32 -> bf16 split: x ~= hi + lo (error ~2^-18 * |x|)
__device__ inline void split2(float x, u16& h, u16& l) {
  unsigned u = __float_as_uint(x);
  unsigned hb = (u + 0x7fffu + ((u >> 16) & 1u)) >> 16;
  float fh = __uint_as_float(hb << 16);
  float r = x - fh;
  unsigned v = __float_as_uint(r);
  unsigned lb = (v + 0x7fffu + ((v >> 16) & 1u)) >> 16;
  h = (u16)hb; l = (u16)lb;
}

__device__ inline uint2 pack4(const u16 a[4]) {
  return make_uint2((unsigned)a[0] | ((unsigned)a[1] << 16),
                    (unsigned)a[2] | ((unsigned)a[3] << 16));
}

__device__ inline u16 f2h(float x) {
  _Float16 h = (_Float16)x;
  u16 r; __builtin_memcpy(&r, &h, 2);
  return r;
}
__device__ inline float h2f(u16 b) {
  _Float16 h; __builtin_memcpy(&h, &b, 2);
  return (float)h;
}
__device__ inline unsigned pkh2(float a, float b) {
  return (unsigned)f2h(a) | ((unsigned)f2h(b) << 16);
}

// fp32 [rows][512] -> u16 [rows][1024] (hi plane | lo plane)
__device__ inline void split_body(const float* __restrict__ in,
                                  u16* __restrict__ out, int e4) {
  const int e = e4 * 4;
  const int m = e >> 9, c = e & 511;
  const float4 v = *(const float4*)(in + e);
  u16 h[4], l[4];
  split2(v.x, h[0], l[0]); split2(v.y, h[1], l[1]);
  split2(v.z, h[2], l[2]); split2(v.w, h[3], l[3]);
  u16* o = out + (size_t)m * 1024 + c;
  *(uint2*)o = pack4(h);
  *(uint2*)(o + 512) = pack4(l);
}

#define GLDS(g, l)                                                        \
  __builtin_amdgcn_global_load_lds(                                       \
      (const __attribute__((address_space(1))) void*)(g),                 \
      (__attribute__((address_space(3))) void*)(l), 16, 0, 0)

// =====================================================================
// prep: fused weight-split + x-split + dense RPE bias build (r11).
// =====================================================================
__global__ __launch_bounds__(256) void prep(
    const float* __restrict__ wq, const float* __restrict__ wk,
    const float* __restrict__ wv, const float* __restrict__ wp,
    const float* __restrict__ xq, const float* __restrict__ xkv,
    const int* __restrict__ cq, const int* __restrict__ ck,
    const float* __restrict__ rpe,
    u16* __restrict__ w2, u16* __restrict__ xq2, u16* __restrict__ xkv2,
    u16* __restrict__ biasT) {
  __shared__ u16 Ts[8 * 16 * 64];  // rpebuild scratch (16 KB)
  const int id = blockIdx.x;
  const int t = threadIdx.x;
  if (id < 1024) {
    const int y = id >> 8;
    const float* src = (y == 0) ? wq : (y == 1) ? wk : (y == 2) ? wv : wp;
    split_body(src, w2 + (size_t)y * 524288, (id & 255) * 256 + t);
  } else if (id < 5120) {
    const int e = id - 1024;
    const int y = e >> 11;
    split_body(y ? xkv : xq, y ? xkv2 : xq2, (e & 2047) * 256 + t);
  } else {
    const int e = id - 5120;
    const int q0 = (e & 15) * 64, k0 = ((e >> 4) & 63) * 16, b = e >> 10;
    const int qn = t & 63, kb = t >> 6;
    const int2 cqv = ((const int2*)cq)[b * NSEQ + q0 + qn];
#pragma unroll
    for (int j = 0; j < 4; ++j) {
      const int k = kb * 4 + j;
      const int2 ckv = ((const int2*)ck)[b * NSEQ + k0 + k];
      const int r0 = min(max(cqv.x - ckv.x + 128, 0), 256);
      const int r1 = min(max(cqv.y - ckv.y + 128, 0), 256);
      const float* rp = rpe + (size_t)(r0 * 257 + r1) * 8;
      const float4 f0 = *(const float4*)rp;
      const float4 f1 = *(const float4*)(rp + 4);
      u16* dst = Ts + k * 64 + qn;
      dst[0 * 1024] = f2h(f0.x * LOG2E); dst[1 * 1024] = f2h(f0.y * LOG2E);
      dst[2 * 1024] = f2h(f0.z * LOG2E); dst[3 * 1024] = f2h(f0.w * LOG2E);
      dst[4 * 1024] = f2h(f1.x * LOG2E); dst[5 * 1024] = f2h(f1.y * LOG2E);
      dst[6 * 1024] = f2h(f1.z * LOG2E); dst[7 * 1024] = f2h(f1.w * LOG2E);
    }
    __syncthreads();
#pragma unroll
    for (int i = 0; i < 4; ++i) {
      const int e2 = i * 256 + t;
      const int row = e2 >> 3, c8 = e2 & 7;  // row = h*16 + k
      const int hh = row >> 4, k = row & 15;
      const uint4 v = *(const uint4*)(Ts + row * 64 + c8 * 8);
      *(uint4*)(biasT + ((size_t)(b * 8 + hh) * 1024 + k0 + k) * 1024 +
                q0 + c8 * 8) = v;
    }
  }
}

// =====================================================================
// Split-bf16 MFMA GEMM v2: 128x128 tile, BK=32, double-buffered LDS,
// ONE barrier per K-iter (attn-verified pipeline: prefetch issued right
// after the barrier, drains a full compute phase later). LDS rows are
// 64 u16 [hi 32k | lo 32k], XOR-8 chunk swizzle (2-way = free).
// 4 waves, each 64x64 (4x4 16-tiles, 48 MFMA/iter). LDS 64 KB ->
// 2 blocks/CU. Grid (M/128, N/128, z) m-major (A-sharers one XCD).
// OUT_MODE: 0 fp32 [m][512]; 3 fp16 [m][512] (scaled);
//           4 fp16 vt layout [(b*512+col)*1024 + k].
// =====================================================================
template <int OUT_MODE>
__device__ __forceinline__ void gemm_db(
    u16 (*__restrict__ As)[8192], u16 (*__restrict__ Bs)[8192],
    const u16* __restrict__ A2, const u16* __restrict__ B2,
    const float* __restrict__ bias, void* __restrict__ outp,
    float scale, int m0, int n0) {
  const int tid = threadIdx.x;
  const int lane = tid & 63, w = tid >> 6;
  const int wm = (w & 1) * 64, wn = (w >> 1) * 64;
  const int lr8 = lane >> 3;
  const int scc = (lane & 7) ^ lr8;       // logical chunk (XOR-8, rows%8==lr8)
  // source column for logical chunk: c<4 -> hi k-chunk, c>=4 -> lo plane
  const int colA = ((scc & 3) * 8) + ((scc >> 2) * 512);

  const int fr = lane & 15, kq = lane >> 4, fx = fr & 7;
  int aoh[4], aol[4], boh[4], bol[4];
#pragma unroll
  for (int i = 0; i < 4; ++i) {
    const int ra = (wm + i * 16 + fr) * 64;
    aoh[i] = ra + ((kq ^ fx)) * 8;
    aol[i] = ra + (((4 + kq) ^ fx)) * 8;
    const int rb = (wn + i * 16 + fr) * 64;
    boh[i] = rb + ((kq ^ fx)) * 8;
    bol[i] = rb + (((4 + kq) ^ fx)) * 8;
  }

  auto stage = [&](int it, int p) {
    const int k0 = it * 32;
#pragma unroll
    for (int i = 0; i < 4; ++i) {
      const int rA = m0 + w * 32 + i * 8 + lr8;
      GLDS(A2 + (size_t)rA * 1024 + colA + k0,
           (char*)As[p] + (w * 32 + i * 8) * 128);
      const int rB = n0 + w * 32 + i * 8 + lr8;
      GLDS(B2 + (size_t)rB * 1024 + colA + k0,
           (char*)Bs[p] + (w * 32 + i * 8) * 128);
    }
  };

  f32x4 acc[4][4] = {};
  stage(0, 0);
  for (int it = 0; it < 16; ++it) {
    const int p = it & 1;
    __syncthreads();  // tile-it staged (a full compute phase in flight)
    if (it + 1 < 16) stage(it + 1, p ^ 1);
    const u16* Ab = As[p];
    const u16* Bb = Bs[p];
    bf16x8 ah[4], al[4], bh[4], bl[4];
#pragma unroll
    for (int i = 0; i < 4; ++i) {
      ah[i] = *(const bf16x8*)(Ab + aoh[i]);
      al[i] = *(const bf16x8*)(Ab + aol[i]);
      bh[i] = *(const bf16x8*)(Bb + boh[i]);
      bl[i] = *(const bf16x8*)(Bb + bol[i]);
    }
#pragma unroll
    for (int i = 0; i < 4; ++i)
#pragma unroll
      for (int j = 0; j < 4; ++j) {
        acc[i][j] = MFMA(al[i], bh[j], acc[i][j]);
        acc[i][j] = MFMA(ah[i], bl[j], acc[i][j]);
        acc[i][j] = MFMA(ah[i], bh[j], acc[i][j]);
      }
  }

  const int er = (lane >> 4) * 4, ec = lane & 15;
#pragma unroll
  for (int i = 0; i < 4; ++i)
#pragma unroll
    for (int j = 0; j < 4; ++j) {
      const int row = m0 + wm + i * 16 + er;
      const int col = n0 + wn + j * 16 + ec;
      const float bv = bias[col];
      if (OUT_MODE == 4) {
        u16 hf[4];
#pragma unroll
        for (int r = 0; r < 4; ++r) hf[r] = f2h((acc[i][j][r] + bv) * scale);
        const int bb = row >> 10, kk = row & 1023;
        *(uint2*)((u16*)outp + ((size_t)(bb * 512 + col)) * 1024 + kk) =
            pack4(hf);
      } else {
#pragma unroll
        for (int r = 0; r < 4; ++r) {
          const float v = (acc[i][j][r] + bv) * scale;
          if (OUT_MODE == 3)
            ((u16*)outp)[(size_t)(row + r) * 512 + col] = f2h(v);
          else
            ((float*)outp)[(size_t)(row + r) * 512 + col] = v;
        }
      }
    }
}

__global__ __launch_bounds__(256, 2) void gemm_qkv(
    const u16* __restrict__ xq2, const u16* __restrict__ xkv2,
    const u16* __restrict__ w2, const float* __restrict__ bq,
    const float* __restrict__ bk, const float* __restrict__ bv,
    u16* __restrict__ q2f, u16* __restrict__ k2f, u16* __restrict__ vtf) {
  __shared__ __align__(16) u16 As[2][8192], Bs[2][8192];
  const int z = blockIdx.z;
  const int m0 = blockIdx.x * 128, n0 = blockIdx.y * 128;
  if (z == 0)
    gemm_db<3>(As, Bs, xq2, w2, bq, q2f, 0.125f * LOG2E, m0, n0);
  else if (z == 1)
    gemm_db<3>(As, Bs, xkv2, w2 + 524288, bk, k2f, 1.0f, m0, n0);
  else
    gemm_db<4>(As, Bs, xkv2, w2 + 2 * 524288, bv, vtf, 1.0f, m0, n0);
}

__global__ __launch_bounds__(256, 2) void gemm_out(
    const u16* __restrict__ xa2, const u16* __restrict__ w2p,
    const float* __restrict__ bp, float* __restrict__ out) {
  __shared__ __align__(16) u16 As[2][8192], Bs[2][8192];
  gemm_db<0>(As, Bs, xa2, w2p, bp, out, 1.0f,
             blockIdx.x * 128, blockIdx.y * 128);
}

// =====================================================================
// fp16 MFMA differential flash attention, v8 (r12 verbatim — 47.7 us,
// kg-split, same-frame merge, 4 waves/SIMD).
// =====================================================================
__global__ __launch_bounds__(512) void attn_f16(
    const u16* __restrict__ q2f, const u16* __restrict__ k2f,
    const u16* __restrict__ vtf, const float* __restrict__ amap,
    const float* __restrict__ lq1, const float* __restrict__ lk1,
    const float* __restrict__ lq2, const float* __restrict__ lk2,
    const u16* __restrict__ biasT, u16* __restrict__ xo) {
  __shared__ __align__(16) u16 KsL[2][2][4096];  // [kg][buf][(h*32+k)*64+d]
  __shared__ __align__(16) u16 VtL[2][2][4096];  // [kg][buf][d*64+(hv*4+kc)^]
  __shared__ float2 mls[2][2][2][16];            // [kg][h][qs][lq] = (m,l)
  __shared__ float l2s[32];
  __shared__ float lam_s;

  const int tid = threadIdx.x;
  const int lane = tid & 63, w = tid >> 6;
  const int kg = w >> 2, h = (w >> 1) & 1, qs = w & 1;
  const int wl = w & 3;
  const int hp = blockIdx.y, b = blockIdx.z;
  const int q0 = blockIdx.x * 32;
  const int head = hp + 4 * h;
  const int lq = lane & 15, lg = lane >> 4;
  const int q = qs * 16 + lq;
  const size_t qrow = (size_t)(b * NSEQ + q0 + q);

  if (tid < 64) {
    float p1 = lq1[hp * 64 + tid] * lk1[hp * 64 + tid];
    float p2 = lq2[hp * 64 + tid] * lk2[hp * 64 + tid];
#pragma unroll
    for (int m = 32; m >= 1; m >>= 1) {
      p1 += __shfl_xor(p1, m, 64);
      p2 += __shfl_xor(p2, m, 64);
    }
    if (tid == 0) lam_s = __expf(p1) - __expf(p2) + 0.8f;
  }

  const float alpha = amap[qrow];

  half8v Qf[2];
#pragma unroll
  for (int ks = 0; ks < 2; ++ks)
    Qf[ks] = *(const half8v*)(q2f + qrow * 512 + head * 64 + ks * 32 + lg * 8);

  f32x4 Ya[4] = {};  // h0: Y1 ; h1: Y3   (own kg/h frame)
  f32x4 Yb[4] = {};  // h1: Y2            (own kg/h frame)
  float m_run = -1e30f, l_run = 0.0f;

  const int lr = lane >> 3;
  const int lc = (lane & 7) ^ lr;
  const int cw = wl * 2;

  auto stage = [&](int it, int p) {
    const int kbase = kg * 512 + it * 32;
#pragma unroll
    for (int i = 0; i < 2; ++i) {
      const int c = cw + i;
      const int row = c * 8 + lr;
      const int sh = row >> 5, k = row & 31;
      const u16* src = k2f + (size_t)(b * NSEQ + kbase + k) * 512 +
                       (hp + 4 * sh) * 64 + lc * 8;
      GLDS(src, (char*)KsL[kg][p] + c * 1024);
    }
#pragma unroll
    for (int i = 0; i < 2; ++i) {
      const int c = cw + i;
      const int d = c * 8 + lr;
      const int hv = lc >> 2, kc = lc & 3;
      const u16* src = vtf + (size_t)(b * 512 + (hp + 4 * hv) * 64 + d) * 1024 +
                       kbase + kc * 8;
      GLDS(src, (char*)VtL[kg][p] + c * 1024);
    }
  };

  const u16* bT = biasT + ((size_t)(b * 8 + head) << 20) + q0 + q;

  stage(0, 0);

  for (int it = 0; it < 16; ++it) {
    const int p = it & 1;
    __syncthreads();
    if (it + 1 < 16) stage(it + 1, p ^ 1);

    u16 rb[8];
    {
      const u16* bt = bT + (size_t)(kg * 512 + it * 32) * 1024;
#pragma unroll
      for (int kt = 0; kt < 2; ++kt)
#pragma unroll
        for (int r = 0; r < 4; ++r)
          rb[kt * 4 + r] = bt[(size_t)(kt * 16 + lg * 4 + r) * 1024];
    }

    const u16* Kb = KsL[kg][p];
    f32x4 st[2] = {};
#pragma unroll
    for (int kt = 0; kt < 2; ++kt) {
      const int krow = kt * 16 + lq;
      const int rx = krow & 7;
#pragma unroll
      for (int ks = 0; ks < 2; ++ks) {
        const int phys = (ks * 4 + lg) ^ rx;
        const half8v kf = *(const half8v*)(Kb + (h * 32 + krow) * 64 + phys * 8);
        st[kt] = MFMAH(kf, Qf[ks], st[kt]);
      }
    }

    float sv[2][4];
    float mx = -1e30f;
#pragma unroll
    for (int kt = 0; kt < 2; ++kt)
#pragma unroll
      for (int r = 0; r < 4; ++r) {
        const float s = st[kt][r] + h2f(rb[kt * 4 + r]);
        sv[kt][r] = s;
        mx = fmaxf(mx, s);
      }
    mx = fmaxf(mx, __shfl_xor(mx, 16, 64));
    mx = fmaxf(mx, __shfl_xor(mx, 32, 64));
    const float mnew = fmaxf(m_run, mx);
    const float a = exp2f(m_run - mnew);
    m_run = mnew;
    float pr[2][4], ps = 0.0f;
#pragma unroll
    for (int kt = 0; kt < 2; ++kt)
#pragma unroll
      for (int r = 0; r < 4; ++r) {
        pr[kt][r] = exp2f(sv[kt][r] - mnew);
        ps += pr[kt][r];
      }
    ps += __shfl_xor(ps, 16, 64);
    ps += __shfl_xor(ps, 32, 64);
    l_run = l_run * a + ps;
#pragma unroll
    for (int dt = 0; dt < 4; ++dt) Ya[dt] *= a;
    if (h == 1) {
#pragma unroll
      for (int dt = 0; dt < 4; ++dt) Yb[dt] *= a;
    }

    const unsigned a0 = pkh2(pr[0][0], pr[0][1]);
    const unsigned a1 = pkh2(pr[0][2], pr[0][3]);
    const unsigned b0 = pkh2(pr[1][0], pr[1][1]);
    const unsigned b1 = pkh2(pr[1][2], pr[1][3]);
    const int srcA = lq + ((lg & 1) << 5);
    const unsigned A0 = __shfl((int)a0, srcA),      A1 = __shfl((int)a1, srcA);
    const unsigned B0 = __shfl((int)b0, srcA),      B1 = __shfl((int)b1, srcA);
    const unsigned C0 = __shfl((int)a0, srcA + 16), C1 = __shfl((int)a1, srcA + 16);
    const unsigned D0 = __shfl((int)b0, srcA + 16), D1 = __shfl((int)b1, srcA + 16);
    const bool t2 = lg >= 2;
    const uint4 Pu = make_uint4(t2 ? B0 : A0, t2 ? B1 : A1,
                                t2 ? D0 : C0, t2 ? D1 : C1);
    half8v pb;
    __builtin_memcpy(&pb, &Pu, 16);

    const u16* Vb = VtL[kg][p];
    if (h == 0) {
#pragma unroll
      for (int dt = 0; dt < 4; ++dt) {
        const int d = dt * 16 + lq;
        const half8v v1 = *(const half8v*)(Vb + d * 64 + ((lg ^ (d & 7))) * 8);
        Ya[dt] = MFMAH(v1, pb, Ya[dt]);
      }
    } else {
#pragma unroll
      for (int dt = 0; dt < 4; ++dt) {
        const int d = dt * 16 + lq;
        const int dx = d & 7;
        const half8v v1 = *(const half8v*)(Vb + d * 64 + ((lg ^ dx)) * 8);
        Yb[dt] = MFMAH(v1, pb, Yb[dt]);
        const half8v v2 = *(const half8v*)(Vb + d * 64 + (((4 + lg) ^ dx)) * 8);
        Ya[dt] = MFMAH(v2, pb, Ya[dt]);
      }
    }
  }

  // ---- kg merge (same-frame rescale; h1 owns Yb so no cross-frame) ----
  float* mY = (float*)KsL;
  float* mB = (float*)VtL;
  __syncthreads();
  if (lane < 16) mls[kg][h][qs][lane] = make_float2(m_run, l_run);
  if (kg == 1) {
#pragma unroll
    for (int dt = 0; dt < 4; ++dt)
#pragma unroll
      for (int r = 0; r < 4; ++r)
        mY[((h * 2 + qs) * 64 + lane) * 16 + dt * 4 + r] = Ya[dt][r];
    if (h == 1) {
#pragma unroll
      for (int dt = 0; dt < 4; ++dt)
#pragma unroll
        for (int r = 0; r < 4; ++r)
          mB[(qs * 64 + lane) * 16 + dt * 4 + r] = Yb[dt][r];
    }
  }
  __syncthreads();
  float l_tot = l_run;
  if (kg == 0) {
    const float2 o = mls[1][h][qs][lq];
    const float mm = fmaxf(m_run, o.x);
    const float s0 = exp2f(m_run - mm);
    const float s1 = exp2f(o.x - mm);
    l_tot = l_run * s0 + o.y * s1;
    const float* sY = mY + ((h * 2 + qs) * 64 + lane) * 16;
#pragma unroll
    for (int dt = 0; dt < 4; ++dt)
#pragma unroll
      for (int r = 0; r < 4; ++r)
        Ya[dt][r] = Ya[dt][r] * s0 + sY[dt * 4 + r] * s1;
    if (h == 1) {
      const float* sB = mB + (qs * 64 + lane) * 16;
#pragma unroll
      for (int dt = 0; dt < 4; ++dt)
#pragma unroll
        for (int r = 0; r < 4; ++r)
          Yb[dt][r] = Yb[dt][r] * s0 + sB[dt * 4 + r] * s1;
    }
  }

  __syncthreads();
  float* y2x = (float*)KsL;
  if (kg == 0 && h == 1) {
    if (lane < 16) l2s[qs * 16 + lane] = l_tot;
#pragma unroll
    for (int dt = 0; dt < 4; ++dt)
#pragma unroll
      for (int r = 0; r < 4; ++r)
        y2x[(qs * 64 + lane) * 16 + dt * 4 + r] = Yb[dt][r];
  }
  __syncthreads();
  if (kg == 0 && h == 1) {
    const float inv2 = 1.0f / l_tot;
#pragma unroll
    for (int dt = 0; dt < 4; ++dt) {
      u16 hh[4], ll[4];
#pragma unroll
      for (int r = 0; r < 4; ++r) split2(Ya[dt][r] * inv2, hh[r], ll[r]);
      u16* o = xo + qrow * 1024 + (hp + 4) * 64 + dt * 16 + lg * 4;
      *(uint2*)o = pack4(hh);
      *(uint2*)(o + 512) = pack4(ll);
    }
  } else if (kg == 0 && h == 0) {
    const float inv1 = 1.0f / l_tot;
    const float inv2 = 1.0f / l2s[qs * 16 + lq];
    const float c1 = (1.0f + alpha) * inv1;
    const float c2 = alpha * lam_s * inv2;
#pragma unroll
    for (int dt = 0; dt < 4; ++dt) {
      u16 hh[4], ll[4];
#pragma unroll
      for (int r = 0; r < 4; ++r) {
        const float y2 = y2x[(qs * 64 + lane) * 16 + dt * 4 + r];
        split2(c1 * Ya[dt][r] - c2 * y2, hh[r], ll[r]);
      }
      u16* o = xo + qrow * 1024 + hp * 64 + dt * 16 + lg * 4;
      *(uint2*)o = pack4(hh);
      *(uint2*)(o + 512) = pack4(ll);
    }
  }
}

// =====================================================================
extern "C" void kernel_launch(void* const* d_in, const int* in_sizes, int n_in,
                              void* d_out, int out_size, void* d_ws, size_t ws_size,
                              hipStream_t stream) {
  const float* x_q   = (const float*)d_in[0];
  const float* x_kv  = (const float*)d_in[1];
  const int*   c_q   = (const int*)d_in[2];
  const int*   c_k   = (const int*)d_in[3];
  const float* alpha = (const float*)d_in[4];
  const float* Wq    = (const float*)d_in[5];
  const float* bq    = (const float*)d_in[6];
  const float* Wk    = (const float*)d_in[7];
  const float* bk    = (const float*)d_in[8];
  const float* Wv    = (const float*)d_in[9];
  const float* bv    = (const float*)d_in[10];
  const float* lq1   = (const float*)d_in[11];
  const float* lk1   = (const float*)d_in[12];
  const float* lq2   = (const float*)d_in[13];
  const float* lk2   = (const float*)d_in[14];
  const float* rpe   = (const float*)d_in[15];
  const float* Wp    = (const float*)d_in[16];
  const float* bp    = (const float*)d_in[17];

  // ws: w2[0,4) | xq2[4,12) (xa aliases after Q-GEMM) | q2f[12,16)
  //     | k2f[16,20) | vtf[20,24) | biasT[28,92).
  // d_out holds xkv2 until gemm_out overwrites it with the result.
  u16* w2    = (u16*)d_ws;
  u16* xq2   = (u16*)((char*)d_ws + (4u << 20));
  u16* q2f   = (u16*)((char*)d_ws + (12u << 20));
  u16* k2f   = (u16*)((char*)d_ws + (16u << 20));
  u16* vtf   = (u16*)((char*)d_ws + (20u << 20));
  u16* xa    = xq2;              // alias: xq2 dead after gemm_qkv
  u16* biasT = (u16*)((char*)d_ws + (28u << 20));
  u16* xkv2  = (u16*)d_out;

  prep<<<9216, 256, 0, stream>>>(Wq, Wk, Wv, Wp, x_q, x_kv, c_q, c_k, rpe,
                                 w2, xq2, xkv2, biasT);
  gemm_qkv<<<dim3(32, 4, 3), 256, 0, stream>>>(xq2, xkv2, w2, bq, bk, bv,
                                               q2f, k2f, vtf);
  attn_f16<<<dim3(32, 4, NB), 512, 0, stream>>>(
      q2f, k2f, vtf, alpha, lq1, lk1, lq2, lk2, biasT, xa);
  gemm_out<<<dim3(32, 4), 256, 0, stream>>>(xa, w2 + 3 * 524288, bp,
                                            (float*)d_out);
}

// Round 14
// 202.839 us; speedup vs baseline: 1.0372x; 1.0372x over previous
//
#include <hip/hip_runtime.h>
#include <cstddef>
#include <cstdint>

#define DIM   512
#define NSEQ  1024
#define NB    4
#define LOG2E 1.44269504f

typedef unsigned short u16;
typedef short bf16x8 __attribute__((ext_vector_type(8)));
typedef _Float16 half8v __attribute__((ext_vector_type(8)));
typedef float f32x4  __attribute__((ext_vector_type(4)));

#define MFMA(a, b, c)  __builtin_amdgcn_mfma_f32_16x16x32_bf16(a, b, c, 0, 0, 0)
#define MFMAH(a, b, c) __builtin_amdgcn_mfma_f32_16x16x32_f16(a, b, c, 0, 0, 0)

// RNE fp32 -> bf16 split: x ~= hi + lo (error ~2^-18 * |x|)
__device__ inline void split2(float x, u16& h, u16& l) {
  unsigned u = __float_as_uint(x);
  unsigned hb = (u + 0x7fffu + ((u >> 16) & 1u)) >> 16;
  float fh = __uint_as_float(hb << 16);
  float r = x - fh;
  unsigned v = __float_as_uint(r);
  unsigned lb = (v + 0x7fffu + ((v >> 16) & 1u)) >> 16;
  h = (u16)hb; l = (u16)lb;
}

__device__ inline uint2 pack4(const u16 a[4]) {
  return make_uint2((unsigned)a[0] | ((unsigned)a[1] << 16),
                    (unsigned)a[2] | ((unsigned)a[3] << 16));
}

__device__ inline u16 f2h(float x) {
  _Float16 h = (_Float16)x;
  u16 r; __builtin_memcpy(&r, &h, 2);
  return r;
}
__device__ inline float h2f(u16 b) {
  _Float16 h; __builtin_memcpy(&h, &b, 2);
  return (float)h;
}
__device__ inline unsigned pkh2(float a, float b) {
  return (unsigned)f2h(a) | ((unsigned)f2h(b) << 16);
}

// fp32 [rows][512] -> u16 [rows][1024] (hi plane | lo plane)
__device__ inline void split_body(const float* __restrict__ in,
                                  u16* __restrict__ out, int e4) {
  const int e = e4 * 4;
  const int m = e >> 9, c = e & 511;
  const float4 v = *(const float4*)(in + e);
  u16 h[4], l[4];
  split2(v.x, h[0], l[0]); split2(v.y, h[1], l[1]);
  split2(v.z, h[2], l[2]); split2(v.w, h[3], l[3]);
  u16* o = out + (size_t)m * 1024 + c;
  *(uint2*)o = pack4(h);
  *(uint2*)(o + 512) = pack4(l);
}

#define GLDS(g, l)                                                        \
  __builtin_amdgcn_global_load_lds(                                       \
      (const __attribute__((address_space(1))) void*)(g),                 \
      (__attribute__((address_space(3))) void*)(l), 16, 0, 0)

// =====================================================================
// prep_split: weight + x split only (no LDS, light streaming kernel).
// blocks [0,1024): W{q,k,v,p}; [1024,5120): x_q / x_kv.
// =====================================================================
__global__ __launch_bounds__(256) void prep_split(
    const float* __restrict__ wq, const float* __restrict__ wk,
    const float* __restrict__ wv, const float* __restrict__ wp,
    const float* __restrict__ xq, const float* __restrict__ xkv,
    u16* __restrict__ w2, u16* __restrict__ xq2, u16* __restrict__ xkv2) {
  const int id = blockIdx.x;
  const int t = threadIdx.x;
  if (id < 1024) {
    const int y = id >> 8;
    const float* src = (y == 0) ? wq : (y == 1) ? wk : (y == 2) ? wv : wp;
    split_body(src, w2 + (size_t)y * 524288, (id & 255) * 256 + t);
  } else {
    const int e = id - 1024;
    const int y = e >> 11;
    split_body(y ? xkv : xq, y ? xkv2 : xq2, (e & 2047) * 256 + t);
  }
}

// =====================================================================
// Split-bf16 MFMA GEMM, 128x128 tile, BK=32, double-buffered, ONE
// barrier per K-iter (r13-verified). LDS rows 64 u16 [hi|lo], XOR-8.
// OUT_MODE: 3 fp16 [m][512] (scaled); 4 fp16 vt [(b*512+col)*1024+k].
// =====================================================================
template <int OUT_MODE>
__device__ __forceinline__ void gemm_db(
    u16 (*__restrict__ As)[8192], u16 (*__restrict__ Bs)[8192],
    const u16* __restrict__ A2, const u16* __restrict__ B2,
    const float* __restrict__ bias, void* __restrict__ outp,
    float scale, int m0, int n0) {
  const int tid = threadIdx.x;
  const int lane = tid & 63, w = tid >> 6;
  const int wm = (w & 1) * 64, wn = (w >> 1) * 64;
  const int lr8 = lane >> 3;
  const int scc = (lane & 7) ^ lr8;
  const int colA = ((scc & 3) * 8) + ((scc >> 2) * 512);

  const int fr = lane & 15, kq = lane >> 4, fx = fr & 7;
  int aoh[4], aol[4], boh[4], bol[4];
#pragma unroll
  for (int i = 0; i < 4; ++i) {
    const int ra = (wm + i * 16 + fr) * 64;
    aoh[i] = ra + ((kq ^ fx)) * 8;
    aol[i] = ra + (((4 + kq) ^ fx)) * 8;
    const int rb = (wn + i * 16 + fr) * 64;
    boh[i] = rb + ((kq ^ fx)) * 8;
    bol[i] = rb + (((4 + kq) ^ fx)) * 8;
  }

  auto stage = [&](int it, int p) {
    const int k0 = it * 32;
#pragma unroll
    for (int i = 0; i < 4; ++i) {
      const int rA = m0 + w * 32 + i * 8 + lr8;
      GLDS(A2 + (size_t)rA * 1024 + colA + k0,
           (char*)As[p] + (w * 32 + i * 8) * 128);
      const int rB = n0 + w * 32 + i * 8 + lr8;
      GLDS(B2 + (size_t)rB * 1024 + colA + k0,
           (char*)Bs[p] + (w * 32 + i * 8) * 128);
    }
  };

  f32x4 acc[4][4] = {};
  stage(0, 0);
  for (int it = 0; it < 16; ++it) {
    const int p = it & 1;
    __syncthreads();
    if (it + 1 < 16) stage(it + 1, p ^ 1);
    const u16* Ab = As[p];
    const u16* Bb = Bs[p];
    bf16x8 ah[4], al[4], bh[4], bl[4];
#pragma unroll
    for (int i = 0; i < 4; ++i) {
      ah[i] = *(const bf16x8*)(Ab + aoh[i]);
      al[i] = *(const bf16x8*)(Ab + aol[i]);
      bh[i] = *(const bf16x8*)(Bb + boh[i]);
      bl[i] = *(const bf16x8*)(Bb + bol[i]);
    }
#pragma unroll
    for (int i = 0; i < 4; ++i)
#pragma unroll
      for (int j = 0; j < 4; ++j) {
        acc[i][j] = MFMA(al[i], bh[j], acc[i][j]);
        acc[i][j] = MFMA(ah[i], bl[j], acc[i][j]);
        acc[i][j] = MFMA(ah[i], bh[j], acc[i][j]);
      }
  }

  const int er = (lane >> 4) * 4, ec = lane & 15;
#pragma unroll
  for (int i = 0; i < 4; ++i)
#pragma unroll
    for (int j = 0; j < 4; ++j) {
      const int row = m0 + wm + i * 16 + er;
      const int col = n0 + wn + j * 16 + ec;
      const float bv = bias[col];
      if (OUT_MODE == 4) {
        u16 hf[4];
#pragma unroll
        for (int r = 0; r < 4; ++r) hf[r] = f2h((acc[i][j][r] + bv) * scale);
        const int bb = row >> 10, kk = row & 1023;
        *(uint2*)((u16*)outp + ((size_t)(bb * 512 + col)) * 1024 + kk) =
            pack4(hf);
      } else {
#pragma unroll
        for (int r = 0; r < 4; ++r)
          ((u16*)outp)[(size_t)(row + r) * 512 + col] =
              f2h((acc[i][j][r] + bv) * scale);
      }
    }
}

// =====================================================================
// Fused QKV GEMMs + rpebuild in ONE dispatch (no data dependency):
// ids [0,384): gemm_db z-slices (MFMA-bound); [384,4480): rpebuild
// (memory-bound) — complementary pipes overlap on the same CUs.
// gemm id = z*128 + y*32 + x keeps the m-major XCD property (ids that
// share an A-tile differ by multiples of 8 -> one XCD).
// =====================================================================
__global__ __launch_bounds__(256) void qkv_rpe(
    const u16* __restrict__ xq2, const u16* __restrict__ xkv2,
    const u16* __restrict__ w2, const float* __restrict__ bq,
    const float* __restrict__ bk, const float* __restrict__ bv,
    u16* __restrict__ q2f, u16* __restrict__ k2f, u16* __restrict__ vtf,
    const int* __restrict__ cq, const int* __restrict__ ck,
    const float* __restrict__ rpe, u16* __restrict__ biasT) {
  __shared__ __align__(16) u16 As[2][8192], Bs[2][8192];
  const int id = blockIdx.x;
  const int t = threadIdx.x;
  if (id < 384) {
    const int z = id >> 7, rem = id & 127;
    const int m0 = (rem & 31) * 128, n0 = (rem >> 5) * 128;
    if (z == 0)
      gemm_db<3>(As, Bs, xq2, w2, bq, q2f, 0.125f * LOG2E, m0, n0);
    else if (z == 1)
      gemm_db<3>(As, Bs, xkv2, w2 + 524288, bk, k2f, 1.0f, m0, n0);
    else
      gemm_db<4>(As, Bs, xkv2, w2 + 2 * 524288, bv, vtf, 1.0f, m0, n0);
  } else {
    // rpebuild body (r11-verified): biasT[b][head][k][q] fp16 * log2e
    u16* Ts = (u16*)As;  // 16 KB scratch
    const int e = id - 384;
    const int q0 = (e & 15) * 64, k0 = ((e >> 4) & 63) * 16, b = e >> 10;
    const int qn = t & 63, kb = t >> 6;
    const int2 cqv = ((const int2*)cq)[b * NSEQ + q0 + qn];
#pragma unroll
    for (int j = 0; j < 4; ++j) {
      const int k = kb * 4 + j;
      const int2 ckv = ((const int2*)ck)[b * NSEQ + k0 + k];
      const int r0 = min(max(cqv.x - ckv.x + 128, 0), 256);
      const int r1 = min(max(cqv.y - ckv.y + 128, 0), 256);
      const float* rp = rpe + (size_t)(r0 * 257 + r1) * 8;
      const float4 f0 = *(const float4*)rp;
      const float4 f1 = *(const float4*)(rp + 4);
      u16* dst = Ts + k * 64 + qn;
      dst[0 * 1024] = f2h(f0.x * LOG2E); dst[1 * 1024] = f2h(f0.y * LOG2E);
      dst[2 * 1024] = f2h(f0.z * LOG2E); dst[3 * 1024] = f2h(f0.w * LOG2E);
      dst[4 * 1024] = f2h(f1.x * LOG2E); dst[5 * 1024] = f2h(f1.y * LOG2E);
      dst[6 * 1024] = f2h(f1.z * LOG2E); dst[7 * 1024] = f2h(f1.w * LOG2E);
    }
    __syncthreads();
#pragma unroll
    for (int i = 0; i < 4; ++i) {
      const int e2 = i * 256 + t;
      const int row = e2 >> 3, c8 = e2 & 7;  // row = h*16 + k
      const int hh = row >> 4, k = row & 15;
      const uint4 v = *(const uint4*)(Ts + row * 64 + c8 * 8);
      *(uint4*)(biasT + ((size_t)(b * 8 + hh) * 1024 + k0 + k) * 1024 +
                q0 + c8 * 8) = v;
    }
  }
}

// =====================================================================
// Output projection: 128x64 tile (r11-verified gemm128 body), fp32 out.
// Grid (32, 8) m-major = 256 blocks (2x the 128x128 grid's fill).
// =====================================================================
__global__ __launch_bounds__(256, 3) void gemm_out(
    const u16* __restrict__ A2, const u16* __restrict__ B2,
    const float* __restrict__ bias, float* __restrict__ out) {
  __shared__ __align__(16) u16 Ah[8192], Al[8192], Bh[4096], Bl[4096];
  const int m0 = blockIdx.x * 128, n0 = blockIdx.y * 64;
  const int tid = threadIdx.x;
  const int lane = tid & 63, w = tid >> 6;
  const int wm = (w & 1) * 64, wn = (w >> 1) * 32;
  const int lr = lane >> 3;
  const int scc = (lane & 7) ^ lr;

  const u16* gA = A2 + (size_t)(m0 + w * 32 + lr) * 1024 + scc * 8;
  const u16* gB = B2 + (size_t)(n0 + w * 16 + lr) * 1024 + scc * 8;
  char* lAh = (char*)Ah + w * 4096;  char* lAl = (char*)Al + w * 4096;
  char* lBh = (char*)Bh + w * 2048;  char* lBl = (char*)Bl + w * 2048;

  const int fr = lane & 15, kq = lane >> 4, fx = fr & 7;
  int aoff[2][4], boff[2][2];
#pragma unroll
  for (int s = 0; s < 2; ++s) {
#pragma unroll
    for (int i = 0; i < 4; ++i)
      aoff[s][i] = (wm + i * 16 + fr) * 64 + (((s * 4 + kq) ^ fx)) * 8;
#pragma unroll
    for (int j = 0; j < 2; ++j)
      boff[s][j] = (wn + j * 16 + fr) * 64 + (((s * 4 + kq) ^ fx)) * 8;
  }

  f32x4 acc[4][2] = {};
  for (int k0 = 0; k0 < 512; k0 += 64) {
    __syncthreads();
#pragma unroll
    for (int i = 0; i < 4; ++i) {
      GLDS(gA + (size_t)i * 8192 + k0, lAh + i * 1024);
      GLDS(gA + (size_t)i * 8192 + 512 + k0, lAl + i * 1024);
    }
#pragma unroll
    for (int i = 0; i < 2; ++i) {
      GLDS(gB + (size_t)i * 8192 + k0, lBh + i * 1024);
      GLDS(gB + (size_t)i * 8192 + 512 + k0, lBl + i * 1024);
    }
    __syncthreads();
#pragma unroll
    for (int s = 0; s < 2; ++s) {
      bf16x8 ah[4], al[4], bh[2], bl[2];
#pragma unroll
      for (int i = 0; i < 4; ++i) {
        ah[i] = *(const bf16x8*)(Ah + aoff[s][i]);
        al[i] = *(const bf16x8*)(Al + aoff[s][i]);
      }
#pragma unroll
      for (int j = 0; j < 2; ++j) {
        bh[j] = *(const bf16x8*)(Bh + boff[s][j]);
        bl[j] = *(const bf16x8*)(Bl + boff[s][j]);
      }
#pragma unroll
      for (int i = 0; i < 4; ++i)
#pragma unroll
        for (int j = 0; j < 2; ++j) {
          acc[i][j] = MFMA(al[i], bh[j], acc[i][j]);
          acc[i][j] = MFMA(ah[i], bl[j], acc[i][j]);
          acc[i][j] = MFMA(ah[i], bh[j], acc[i][j]);
        }
    }
  }

  const int er = (lane >> 4) * 4, ec = lane & 15;
#pragma unroll
  for (int i = 0; i < 4; ++i)
#pragma unroll
    for (int j = 0; j < 2; ++j) {
      const int row = m0 + wm + i * 16 + er;
      const int col = n0 + wn + j * 16 + ec;
      const float bv = bias[col];
#pragma unroll
      for (int r = 0; r < 4; ++r)
        out[(size_t)(row + r) * 512 + col] = acc[i][j][r] + bv;
    }
}

// =====================================================================
// fp16 MFMA differential flash attention (r12 verbatim — 47.7 us).
// =====================================================================
__global__ __launch_bounds__(512) void attn_f16(
    const u16* __restrict__ q2f, const u16* __restrict__ k2f,
    const u16* __restrict__ vtf, const float* __restrict__ amap,
    const float* __restrict__ lq1, const float* __restrict__ lk1,
    const float* __restrict__ lq2, const float* __restrict__ lk2,
    const u16* __restrict__ biasT, u16* __restrict__ xo) {
  __shared__ __align__(16) u16 KsL[2][2][4096];
  __shared__ __align__(16) u16 VtL[2][2][4096];
  __shared__ float2 mls[2][2][2][16];
  __shared__ float l2s[32];
  __shared__ float lam_s;

  const int tid = threadIdx.x;
  const int lane = tid & 63, w = tid >> 6;
  const int kg = w >> 2, h = (w >> 1) & 1, qs = w & 1;
  const int wl = w & 3;
  const int hp = blockIdx.y, b = blockIdx.z;
  const int q0 = blockIdx.x * 32;
  const int head = hp + 4 * h;
  const int lq = lane & 15, lg = lane >> 4;
  const int q = qs * 16 + lq;
  const size_t qrow = (size_t)(b * NSEQ + q0 + q);

  if (tid < 64) {
    float p1 = lq1[hp * 64 + tid] * lk1[hp * 64 + tid];
    float p2 = lq2[hp * 64 + tid] * lk2[hp * 64 + tid];
#pragma unroll
    for (int m = 32; m >= 1; m >>= 1) {
      p1 += __shfl_xor(p1, m, 64);
      p2 += __shfl_xor(p2, m, 64);
    }
    if (tid == 0) lam_s = __expf(p1) - __expf(p2) + 0.8f;
  }

  const float alpha = amap[qrow];

  half8v Qf[2];
#pragma unroll
  for (int ks = 0; ks < 2; ++ks)
    Qf[ks] = *(const half8v*)(q2f + qrow * 512 + head * 64 + ks * 32 + lg * 8);

  f32x4 Ya[4] = {};
  f32x4 Yb[4] = {};
  float m_run = -1e30f, l_run = 0.0f;

  const int lr = lane >> 3;
  const int lc = (lane & 7) ^ lr;
  const int cw = wl * 2;

  auto stage = [&](int it, int p) {
    const int kbase = kg * 512 + it * 32;
#pragma unroll
    for (int i = 0; i < 2; ++i) {
      const int c = cw + i;
      const int row = c * 8 + lr;
      const int sh = row >> 5, k = row & 31;
      const u16* src = k2f + (size_t)(b * NSEQ + kbase + k) * 512 +
                       (hp + 4 * sh) * 64 + lc * 8;
      GLDS(src, (char*)KsL[kg][p] + c * 1024);
    }
#pragma unroll
    for (int i = 0; i < 2; ++i) {
      const int c = cw + i;
      const int d = c * 8 + lr;
      const int hv = lc >> 2, kc = lc & 3;
      const u16* src = vtf + (size_t)(b * 512 + (hp + 4 * hv) * 64 + d) * 1024 +
                       kbase + kc * 8;
      GLDS(src, (char*)VtL[kg][p] + c * 1024);
    }
  };

  const u16* bT = biasT + ((size_t)(b * 8 + head) << 20) + q0 + q;

  stage(0, 0);

  for (int it = 0; it < 16; ++it) {
    const int p = it & 1;
    __syncthreads();
    if (it + 1 < 16) stage(it + 1, p ^ 1);

    u16 rb[8];
    {
      const u16* bt = bT + (size_t)(kg * 512 + it * 32) * 1024;
#pragma unroll
      for (int kt = 0; kt < 2; ++kt)
#pragma unroll
        for (int r = 0; r < 4; ++r)
          rb[kt * 4 + r] = bt[(size_t)(kt * 16 + lg * 4 + r) * 1024];
    }

    const u16* Kb = KsL[kg][p];
    f32x4 st[2] = {};
#pragma unroll
    for (int kt = 0; kt < 2; ++kt) {
      const int krow = kt * 16 + lq;
      const int rx = krow & 7;
#pragma unroll
      for (int ks = 0; ks < 2; ++ks) {
        const int phys = (ks * 4 + lg) ^ rx;
        const half8v kf = *(const half8v*)(Kb + (h * 32 + krow) * 64 + phys * 8);
        st[kt] = MFMAH(kf, Qf[ks], st[kt]);
      }
    }

    float sv[2][4];
    float mx = -1e30f;
#pragma unroll
    for (int kt = 0; kt < 2; ++kt)
#pragma unroll
      for (int r = 0; r < 4; ++r) {
        const float s = st[kt][r] + h2f(rb[kt * 4 + r]);
        sv[kt][r] = s;
        mx = fmaxf(mx, s);
      }
    mx = fmaxf(mx, __shfl_xor(mx, 16, 64));
    mx = fmaxf(mx, __shfl_xor(mx, 32, 64));
    const float mnew = fmaxf(m_run, mx);
    const float a = exp2f(m_run - mnew);
    m_run = mnew;
    float pr[2][4], ps = 0.0f;
#pragma unroll
    for (int kt = 0; kt < 2; ++kt)
#pragma unroll
      for (int r = 0; r < 4; ++r) {
        pr[kt][r] = exp2f(sv[kt][r] - mnew);
        ps += pr[kt][r];
      }
    ps += __shfl_xor(ps, 16, 64);
    ps += __shfl_xor(ps, 32, 64);
    l_run = l_run * a + ps;
#pragma unroll
    for (int dt = 0; dt < 4; ++dt) Ya[dt] *= a;
    if (h == 1) {
#pragma unroll
      for (int dt = 0; dt < 4; ++dt) Yb[dt] *= a;
    }

    const unsigned a0 = pkh2(pr[0][0], pr[0][1]);
    const unsigned a1 = pkh2(pr[0][2], pr[0][3]);
    const unsigned b0 = pkh2(pr[1][0], pr[1][1]);
    const unsigned b1 = pkh2(pr[1][2], pr[1][3]);
    const int srcA = lq + ((lg & 1) << 5);
    const unsigned A0 = __shfl((int)a0, srcA),      A1 = __shfl((int)a1, srcA);
    const unsigned B0 = __shfl((int)b0, srcA),      B1 = __shfl((int)b1, srcA);
    const unsigned C0 = __shfl((int)a0, srcA + 16), C1 = __shfl((int)a1, srcA + 16);
    const unsigned D0 = __shfl((int)b0, srcA + 16), D1 = __shfl((int)b1, srcA + 16);
    const bool t2 = lg >= 2;
    const uint4 Pu = make_uint4(t2 ? B0 : A0, t2 ? B1 : A1,
                                t2 ? D0 : C0, t2 ? D1 : C1);
    half8v pb;
    __builtin_memcpy(&pb, &Pu, 16);

    const u16* Vb = VtL[kg][p];
    if (h == 0) {
#pragma unroll
      for (int dt = 0; dt < 4; ++dt) {
        const int d = dt * 16 + lq;
        const half8v v1 = *(const half8v*)(Vb + d * 64 + ((lg ^ (d & 7))) * 8);
        Ya[dt] = MFMAH(v1, pb, Ya[dt]);
      }
    } else {
#pragma unroll
      for (int dt = 0; dt < 4; ++dt) {
        const int d = dt * 16 + lq;
        const int dx = d & 7;
        const half8v v1 = *(const half8v*)(Vb + d * 64 + ((lg ^ dx)) * 8);
        Yb[dt] = MFMAH(v1, pb, Yb[dt]);
        const half8v v2 = *(const half8v*)(Vb + d * 64 + (((4 + lg) ^ dx)) * 8);
        Ya[dt] = MFMAH(v2, pb, Ya[dt]);
      }
    }
  }

  float* mY = (float*)KsL;
  float* mB = (float*)VtL;
  __syncthreads();
  if (lane < 16) mls[kg][h][qs][lane] = make_float2(m_run, l_run);
  if (kg == 1) {
#pragma unroll
    for (int dt = 0; dt < 4; ++dt)
#pragma unroll
      for (int r = 0; r < 4; ++r)
        mY[((h * 2 + qs) * 64 + lane) * 16 + dt * 4 + r] = Ya[dt][r];
    if (h == 1) {
#pragma unroll
      for (int dt = 0; dt < 4; ++dt)
#pragma unroll
        for (int r = 0; r < 4; ++r)
          mB[(qs * 64 + lane) * 16 + dt * 4 + r] = Yb[dt][r];
    }
  }
  __syncthreads();
  float l_tot = l_run;
  if (kg == 0) {
    const float2 o = mls[1][h][qs][lq];
    const float mm = fmaxf(m_run, o.x);
    const float s0 = exp2f(m_run - mm);
    const float s1 = exp2f(o.x - mm);
    l_tot = l_run * s0 + o.y * s1;
    const float* sY = mY + ((h * 2 + qs) * 64 + lane) * 16;
#pragma unroll
    for (int dt = 0; dt < 4; ++dt)
#pragma unroll
      for (int r = 0; r < 4; ++r)
        Ya[dt][r] = Ya[dt][r] * s0 + sY[dt * 4 + r] * s1;
    if (h == 1) {
      const float* sB = mB + (qs * 64 + lane) * 16;
#pragma unroll
      for (int dt = 0; dt < 4; ++dt)
#pragma unroll
        for (int r = 0; r < 4; ++r)
          Yb[dt][r] = Yb[dt][r] * s0 + sB[dt * 4 + r] * s1;
    }
  }

  __syncthreads();
  float* y2x = (float*)KsL;
  if (kg == 0 && h == 1) {
    if (lane < 16) l2s[qs * 16 + lane] = l_tot;
#pragma unroll
    for (int dt = 0; dt < 4; ++dt)
#pragma unroll
      for (int r = 0; r < 4; ++r)
        y2x[(qs * 64 + lane) * 16 + dt * 4 + r] = Yb[dt][r];
  }
  __syncthreads();
  if (kg == 0 && h == 1) {
    const float inv2 = 1.0f / l_tot;
#pragma unroll
    for (int dt = 0; dt < 4; ++dt) {
      u16 hh[4], ll[4];
#pragma unroll
      for (int r = 0; r < 4; ++r) split2(Ya[dt][r] * inv2, hh[r], ll[r]);
      u16* o = xo + qrow * 1024 + (hp + 4) * 64 + dt * 16 + lg * 4;
      *(uint2*)o = pack4(hh);
      *(uint2*)(o + 512) = pack4(ll);
    }
  } else if (kg == 0 && h == 0) {
    const float inv1 = 1.0f / l_tot;
    const float inv2 = 1.0f / l2s[qs * 16 + lq];
    const float c1 = (1.0f + alpha) * inv1;
    const float c2 = alpha * lam_s * inv2;
#pragma unroll
    for (int dt = 0; dt < 4; ++dt) {
      u16 hh[4], ll[4];
#pragma unroll
      for (int r = 0; r < 4; ++r) {
        const float y2 = y2x[(qs * 64 + lane) * 16 + dt * 4 + r];
        split2(c1 * Ya[dt][r] - c2 * y2, hh[r], ll[r]);
      }
      u16* o = xo + qrow * 1024 + hp * 64 + dt * 16 + lg * 4;
      *(uint2*)o = pack4(hh);
      *(uint2*)(o + 512) = pack4(ll);
    }
  }
}

// =====================================================================
extern "C" void kernel_launch(void* const* d_in, const int* in_sizes, int n_in,
                              void* d_out, int out_size, void* d_ws, size_t ws_size,
                              hipStream_t stream) {
  const float* x_q   = (const float*)d_in[0];
  const float* x_kv  = (const float*)d_in[1];
  const int*   c_q   = (const int*)d_in[2];
  const int*   c_k   = (const int*)d_in[3];
  const float* alpha = (const float*)d_in[4];
  const float* Wq    = (const float*)d_in[5];
  const float* bq    = (const float*)d_in[6];
  const float* Wk    = (const float*)d_in[7];
  const float* bk    = (const float*)d_in[8];
  const float* Wv    = (const float*)d_in[9];
  const float* bv    = (const float*)d_in[10];
  const float* lq1   = (const float*)d_in[11];
  const float* lk1   = (const float*)d_in[12];
  const float* lq2   = (const float*)d_in[13];
  const float* lk2   = (const float*)d_in[14];
  const float* rpe   = (const float*)d_in[15];
  const float* Wp    = (const float*)d_in[16];
  const float* bp    = (const float*)d_in[17];

  // ws: w2[0,4) | xq2[4,12) (xa aliases after gemm) | q2f[12,16)
  //     | k2f[16,20) | vtf[20,24) | biasT[28,92).
  // d_out holds xkv2 until gemm_out overwrites it with the result.
  u16* w2    = (u16*)d_ws;
  u16* xq2   = (u16*)((char*)d_ws + (4u << 20));
  u16* q2f   = (u16*)((char*)d_ws + (12u << 20));
  u16* k2f   = (u16*)((char*)d_ws + (16u << 20));
  u16* vtf   = (u16*)((char*)d_ws + (20u << 20));
  u16* xa    = xq2;              // alias: xq2 dead after qkv_rpe
  u16* biasT = (u16*)((char*)d_ws + (28u << 20));
  u16* xkv2  = (u16*)d_out;

  prep_split<<<5120, 256, 0, stream>>>(Wq, Wk, Wv, Wp, x_q, x_kv,
                                       w2, xq2, xkv2);
  qkv_rpe<<<4480, 256, 0, stream>>>(xq2, xkv2, w2, bq, bk, bv,
                                    q2f, k2f, vtf, c_q, c_k, rpe, biasT);
  attn_f16<<<dim3(32, 4, NB), 512, 0, stream>>>(
      q2f, k2f, vtf, alpha, lq1, lk1, lq2, lk2, biasT, xa);
  gemm_out<<<dim3(32, 8), 256, 0, stream>>>(xa, w2 + 3 * 524288, bp,
                                            (float*)d_out);
}